// Round 1
// baseline (223.133 us; speedup 1.0000x reference)
//
#include <hip/hip_runtime.h>
#include <math.h>

#define D_DIM 1024
#define F3    192   // 64 top + 64 feat + 64 gates
#define TOKS  32    // tokens per block
#define DK    32    // D-chunk staged in LDS

// Pack W_top[D][64], W_feat[D][64], W_gates[64][D] into f-major WcT[D][192]
// so the main kernel's LDS staging is a flat contiguous copy.
__global__ __launch_bounds__(256) void pack_w_kernel(
    const float* __restrict__ Wt, const float* __restrict__ Wf,
    const float* __restrict__ Wg, float* __restrict__ WcT) {
  int e = blockIdx.x * 256 + threadIdx.x;
  if (e >= D_DIM * F3) return;
  int d = e / F3;
  int f = e - d * F3;
  float v;
  if (f < 64)       v = Wt[d * 64 + f];
  else if (f < 128) v = Wf[d * 64 + (f - 64)];
  else              v = Wg[(f - 128) * D_DIM + d];   // transpose of W_gates
  WcT[e] = v;
}

// 256 threads = 16 token-groups x 16 feature-groups.
// Thread (tg,fg): tokens {2tg, 2tg+1} x features [12fg, 12fg+12)  -> acc 2x12.
__global__ __launch_bounds__(256, 2) void moe_gate_kernel(
    const float* __restrict__ x, const float* __restrict__ WcT,
    const float* __restrict__ b_top, const float* __restrict__ b_feat,
    const float* __restrict__ b_gates, const float* __restrict__ alpha,
    const int* __restrict__ nump, float* __restrict__ out) {
  __shared__ float smem[7296];           // 29.2 KB -> 2 blocks/CU fits easily
  float* xs  = smem;                     // x tile  [32][36] (pad: stride 36)
  float* wsm = smem + 32 * 36;           // w tile  [DK][192]
  const int tid  = threadIdx.x;
  const int tg   = tid >> 4;             // 0..15
  const int fg   = tid & 15;             // 0..15
  const int tok0 = blockIdx.x * TOKS;

  float a0[12], a1[12];
#pragma unroll
  for (int j = 0; j < 12; ++j) { a0[j] = 0.f; a1[j] = 0.f; }

  for (int d0 = 0; d0 < D_DIM; d0 += DK) {
    // stage x tile [32 toks][32 d]: one float4 per thread, coalesced
    {
      int r = tid >> 3, c = (tid & 7) << 2;
      float4 v = *(const float4*)(x + (long)(tok0 + r) * D_DIM + d0 + c);
      *(float4*)(xs + r * 36 + c) = v;
    }
    // stage W tile: rows d0..d0+DK of WcT are contiguous -> flat copy 6144 floats
    {
      const float* src = WcT + (long)d0 * F3;
#pragma unroll
      for (int k = 0; k < 6; ++k) {
        int e4 = tid + k * 256;
        float4 v = *(const float4*)(src + e4 * 4);
        *(float4*)(wsm + e4 * 4) = v;
      }
    }
    __syncthreads();

    const float* wb  = wsm + fg * 12;
    const float* xb0 = xs + (tg * 2 + 0) * 36;
    const float* xb1 = xs + (tg * 2 + 1) * 36;
#pragma unroll 8
    for (int dd = 0; dd < DK; ++dd) {
      float xv0 = xb0[dd];               // 4 distinct addrs/wave, 16-lane bcast
      float xv1 = xb1[dd];
      float wv[12];                      // 3x ds_read_b128, 2-way (free)
      *(float4*)(wv + 0) = *(const float4*)(wb + dd * F3 + 0);
      *(float4*)(wv + 4) = *(const float4*)(wb + dd * F3 + 4);
      *(float4*)(wv + 8) = *(const float4*)(wb + dd * F3 + 8);
#pragma unroll
      for (int j = 0; j < 12; ++j) {
        a0[j] = fmaf(xv0, wv[j], a0[j]);
        a1[j] = fmaf(xv1, wv[j], a1[j]);
      }
    }
    __syncthreads();
  }

  // ---- epilogue: logits(+bias) -> LDS [32][197] (197: bank-spread for rows)
  float* L = smem;
#pragma unroll
  for (int j = 0; j < 12; ++j) {
    int f = fg * 12 + j;
    float b = (f < 64) ? b_top[f] : (f < 128 ? b_feat[f - 64] : b_gates[f - 128]);
    L[(tg * 2 + 0) * 197 + f] = a0[j] + b;
    L[(tg * 2 + 1) * 197 + f] = a1[j] + b;
  }
  __syncthreads();

  if (tid < TOKS) {
    const float* Lr = L + tid * 197;     // [0,64): top  [64,128): feat  [128,192): gates
    float a = 1.f / (1.f + expf(-alpha[0]));
    int num = *nump;
    num = num < 1 ? 1 : (num > 64 ? 64 : num);

    // top-k (strict > scan ascending f => lowest-index tie-break, matches lax.top_k)
    unsigned long long sel = 0ull;
    float m0 = 0.f, Zt = 0.f, St = 0.f;
    for (int k = 0; k < num; ++k) {
      float best = -3.4e38f; int bi = 0;
      for (int f = 0; f < 64; ++f) {
        if ((sel >> f) & 1ull) continue;
        float v = Lr[f];
        if (v > best) { best = v; bi = f; }
      }
      sel |= (1ull << bi);
      if (k == 0) m0 = best;             // first pick = overall max
      float e = expf(best - m0);
      Zt += e;
      float g = 1.f / (1.f + expf(-Lr[128 + bi]));
      St = fmaf(g, e, St);
    }

    // dense branch: sum_f sigmoid(gate_f) * softmax(feat)_f, fused
    float mf = -3.4e38f;
    for (int f = 0; f < 64; ++f) mf = fmaxf(mf, Lr[64 + f]);
    float Zf = 0.f, Sf = 0.f;
    for (int f = 0; f < 64; ++f) {
      float e = expf(Lr[64 + f] - mf);
      Zf += e;
      float g = 1.f / (1.f + expf(-Lr[128 + f]));
      Sf = fmaf(g, e, Sf);
    }
    out[tok0 + tid] = a * (St / Zt) + (1.f - a) * (Sf / Zf);
  }
}

extern "C" void kernel_launch(void* const* d_in, const int* in_sizes, int n_in,
                              void* d_out, int out_size, void* d_ws, size_t ws_size,
                              hipStream_t stream) {
  const float* x       = (const float*)d_in[0];
  const float* W_top   = (const float*)d_in[1];
  const float* b_top   = (const float*)d_in[2];
  const float* W_feat  = (const float*)d_in[3];
  const float* b_feat  = (const float*)d_in[4];
  const float* W_gates = (const float*)d_in[5];
  const float* b_gates = (const float*)d_in[6];
  const float* alpha   = (const float*)d_in[7];
  const int*   nump    = (const int*)d_in[8];
  float*       out     = (float*)d_out;
  float*       WcT     = (float*)d_ws;   // 192*1024 floats = 768 KB

  int n_tok = in_sizes[0] / D_DIM;       // 16384
  hipLaunchKernelGGL(pack_w_kernel, dim3((D_DIM * F3 + 255) / 256), dim3(256), 0,
                     stream, W_top, W_feat, W_gates, WcT);
  hipLaunchKernelGGL(moe_gate_kernel, dim3(n_tok / TOKS), dim3(256), 0, stream,
                     x, WcT, b_top, b_feat, b_gates, alpha, nump, out);
}

// Round 2
// 153.457 us; speedup vs baseline: 1.4540x; 1.4540x over previous
//
#include <hip/hip_runtime.h>
#include <math.h>

#define D_DIM  1024
#define F3     192          // 64 top | 64 feat | 64 gates
#define TOKB   64           // tokens per block
#define KC     64           // K-chunk
#define NCH    (D_DIM / KC) // 16 chunks
#define THREADS 512         // 8 waves: wr(2) x wc(4)
// Wp layout (ushort bf16 bits): [chunk 16][frag ff 48][lane 64][j 8]
//   ff = (kk*12 + fb)*2 + pl ; kk = 32-slice in chunk, fb = feature block(16), pl = hi/lo
//   element (lane,j): k = chunk*64 + kk*32 + (lane>>4)*8 + j ; f = fb*16 + (lane&15)
#define WP_CHUNK_ELEMS (48 * 64 * 8)   // 24576 ushorts = 48 KB

typedef short  bf16x8 __attribute__((ext_vector_type(8)));
typedef float  f32x4  __attribute__((ext_vector_type(4)));
typedef ushort u16x4  __attribute__((ext_vector_type(4)));
typedef ushort u16x8  __attribute__((ext_vector_type(8)));

__device__ __forceinline__ ushort f2bf(float f) {      // RTNE fp32 -> bf16 bits
  uint u = __float_as_uint(f);
  return (ushort)((u + 0x7fffu + ((u >> 16) & 1u)) >> 16);
}
__device__ __forceinline__ float bf2f(ushort h) {
  return __uint_as_float(((uint)h) << 16);
}
__device__ __forceinline__ void gload16(const void* g, void* l) {
  __builtin_amdgcn_global_load_lds((const __attribute__((address_space(1))) void*)g,
                                   (__attribute__((address_space(3))) void*)l, 16, 0, 0);
}

// Pack W_top/W_feat/W_gates^T into MFMA-B-fragment-ordered bf16 hi/lo planes.
__global__ __launch_bounds__(256) void pack_w_kernel(
    const float* __restrict__ Wt, const float* __restrict__ Wf,
    const float* __restrict__ Wg, ushort* __restrict__ Wp) {
  int e = blockIdx.x * 256 + threadIdx.x;      // 0..24575 : (kc, kk, fb, lane)
  if (e >= 16 * 2 * 12 * 64) return;
  int lane = e & 63;
  int rest = e >> 6;
  int fb   = rest % 12;
  int r2   = rest / 12;
  int kk   = r2 & 1;
  int kc   = r2 >> 1;
  int k0   = kc * 64 + kk * 32 + ((lane >> 4) * 8);
  int f    = fb * 16 + (lane & 15);
  u16x8 H, L;
#pragma unroll
  for (int j = 0; j < 8; ++j) {
    int k = k0 + j;
    float v = (f < 64)  ? Wt[k * 64 + f]
            : (f < 128) ? Wf[k * 64 + (f - 64)]
                        : Wg[(f - 128) * D_DIM + k];
    ushort h = f2bf(v);
    H[j] = h;
    L[j] = f2bf(v - bf2f(h));
  }
  size_t base = ((size_t)(kc * 48 + (kk * 12 + fb) * 2) * 64 + lane) * 8;
  *(u16x8*)(Wp + base)       = H;              // pl=0 (hi)
  *(u16x8*)(Wp + base + 512) = L;              // pl=1 (lo), +64 lanes*8
}

// LDS map (bytes):
//   xh: [0, 9216)           64 x 72 bf16 (stride 72 = even bank spread)
//   xl: [9216, 18432)
//   B0: [18432, 67584)      48 KB fragment-ordered chunk buffer
//   B1: [67584, 116736)
//   bsm:[116736, 117504)    192 fp32 biases
//   L (epilogue overlay at 0): 64 x 197 fp32 = 50432 B
__global__ __launch_bounds__(THREADS) void moe_gate_kernel(
    const float* __restrict__ x, const ushort* __restrict__ Wp,
    const float* __restrict__ b_top, const float* __restrict__ b_feat,
    const float* __restrict__ b_gates, const float* __restrict__ alpha,
    const int* __restrict__ nump, float* __restrict__ out) {
  __shared__ __align__(16) char smem[117504];
  ushort* xh  = (ushort*)smem;
  ushort* xl  = (ushort*)(smem + 9216);
  char*   B0  = smem + 18432;
  char*   B1  = smem + 67584;
  float*  bsm = (float*)(smem + 116736);

  const int tid  = threadIdx.x;
  const int lane = tid & 63;
  const int wid  = tid >> 6;          // 0..7
  const int wr   = wid >> 2;          // 0..1  (32-token row group)
  const int wc   = wid & 3;           // 0..3  (48-feature col group)
  const int tok0 = blockIdx.x * TOKB;

  if (tid < F3)
    bsm[tid] = (tid < 64) ? b_top[tid]
             : (tid < 128) ? b_feat[tid - 64] : b_gates[tid - 128];

  // per-thread x staging coords: row = tid>>3 (token-local), cols (tid&7)*4 and +32
  const int xrow = tid >> 3;
  const int xcol = (tid & 7) * 4;
  const float* xp = x + (size_t)(tok0 + xrow) * D_DIM + xcol;

  // ---- prologue: prefetch chunk 0 (x -> regs, W -> LDS B0)
  f32x4 xr0 = *(const f32x4*)(xp);
  f32x4 xr1 = *(const f32x4*)(xp + 32);
  {
    const ushort* src = Wp + (size_t)wid * 512 + (size_t)lane * 8;
    char* dst = B0 + wid * 1024;
#pragma unroll
    for (int p = 0; p < 6; ++p) gload16(src + p * 4096, dst + p * 8192);
  }

  // A-fragment LDS byte offsets (within a plane): row*144 + kk*64 + (lane>>4)*16
  const int aoff0 = (wr * 32 + (lane & 15)) * 144 + ((lane >> 4) * 16);
  const int aoff1 = aoff0 + 16 * 144;

  f32x4 acc[2][3] = {};

  for (int c = 0; c < NCH; ++c) {
    // 1. publish x chunk c (regs -> bf16 hi/lo planes)
    {
      u16x4 h0, l0, h1, l1;
#pragma unroll
      for (int i = 0; i < 4; ++i) {
        float v0 = xr0[i], v1 = xr1[i];
        ushort a = f2bf(v0); h0[i] = a; l0[i] = f2bf(v0 - bf2f(a));
        ushort b = f2bf(v1); h1[i] = b; l1[i] = f2bf(v1 - bf2f(b));
      }
      *(u16x4*)(xh + xrow * 72 + xcol)      = h0;
      *(u16x4*)(xl + xrow * 72 + xcol)      = l0;
      *(u16x4*)(xh + xrow * 72 + xcol + 32) = h1;
      *(u16x4*)(xl + xrow * 72 + xcol + 32) = l1;
    }
    __syncthreads();   // publishes x writes; drains B(c) global_load_lds

    // 2. issue prefetch for chunk c+1 (overlaps compute below)
    if (c < NCH - 1) {
      const float* xpn = xp + (c + 1) * KC;
      xr0 = *(const f32x4*)(xpn);
      xr1 = *(const f32x4*)(xpn + 32);
      const ushort* src = Wp + (size_t)(c + 1) * WP_CHUNK_ELEMS + wid * 512 + lane * 8;
      char* dst = (((c + 1) & 1) ? B1 : B0) + wid * 1024;
#pragma unroll
      for (int p = 0; p < 6; ++p) gload16(src + p * 4096, dst + p * 8192);
    }

    // 3. compute chunk c: 36 MFMA/wave
    const char* Bc = (c & 1) ? B1 : B0;
#pragma unroll
    for (int kk = 0; kk < 2; ++kk) {
      bf16x8 ah0 = *(const bf16x8*)((const char*)xh + aoff0 + kk * 64);
      bf16x8 ah1 = *(const bf16x8*)((const char*)xh + aoff1 + kk * 64);
      bf16x8 al0 = *(const bf16x8*)((const char*)xl + aoff0 + kk * 64);
      bf16x8 al1 = *(const bf16x8*)((const char*)xl + aoff1 + kk * 64);
#pragma unroll
      for (int fbl = 0; fbl < 3; ++fbl) {
        const char* bp = Bc + ((kk * 12 + wc * 3 + fbl) * 2) * 1024 + lane * 16;
        bf16x8 bh = *(const bf16x8*)bp;
        bf16x8 bl = *(const bf16x8*)(bp + 1024);
        acc[0][fbl] = __builtin_amdgcn_mfma_f32_16x16x32_bf16(ah0, bh, acc[0][fbl], 0, 0, 0);
        acc[0][fbl] = __builtin_amdgcn_mfma_f32_16x16x32_bf16(ah0, bl, acc[0][fbl], 0, 0, 0);
        acc[0][fbl] = __builtin_amdgcn_mfma_f32_16x16x32_bf16(al0, bh, acc[0][fbl], 0, 0, 0);
        acc[1][fbl] = __builtin_amdgcn_mfma_f32_16x16x32_bf16(ah1, bh, acc[1][fbl], 0, 0, 0);
        acc[1][fbl] = __builtin_amdgcn_mfma_f32_16x16x32_bf16(ah1, bl, acc[1][fbl], 0, 0, 0);
        acc[1][fbl] = __builtin_amdgcn_mfma_f32_16x16x32_bf16(al1, bh, acc[1][fbl], 0, 0, 0);
      }
    }
    __syncthreads();   // protect xh/xl + B[buf] before next overwrite
  }

  // ---- epilogue: logits + bias -> LDS L[64][197]
  float* L = (float*)smem;
#pragma unroll
  for (int rf = 0; rf < 2; ++rf)
#pragma unroll
    for (int fbl = 0; fbl < 3; ++fbl) {
      int tl = wr * 32 + rf * 16 + ((lane >> 4) * 4);
      int f  = wc * 48 + fbl * 16 + (lane & 15);
      float bv = bsm[f];
#pragma unroll
      for (int r = 0; r < 4; ++r)
        L[(tl + r) * 197 + f] = acc[rf][fbl][r] + bv;
    }
  __syncthreads();

  if (tid < TOKB) {
    const float* Lr = L + tid * 197;  // [0,64) top | [64,128) feat | [128,192) gates
    float a = 1.f / (1.f + expf(-alpha[0]));
    int num = *nump;
    num = num < 1 ? 1 : (num > 64 ? 64 : num);

    unsigned long long sel = 0ull;
    float m0 = 0.f, Zt = 0.f, St = 0.f;
    for (int k = 0; k < num; ++k) {
      float best = -3.4e38f; int bi = 0;
      for (int f = 0; f < 64; ++f) {
        if ((sel >> f) & 1ull) continue;
        float v = Lr[f];
        if (v > best) { best = v; bi = f; }
      }
      sel |= (1ull << bi);
      if (k == 0) m0 = best;
      float e = expf(best - m0);
      Zt += e;
      float g = 1.f / (1.f + expf(-Lr[128 + bi]));
      St = fmaf(g, e, St);
    }
    float mf = -3.4e38f;
    for (int f = 0; f < 64; ++f) mf = fmaxf(mf, Lr[64 + f]);
    float Zf = 0.f, Sf = 0.f;
    for (int f = 0; f < 64; ++f) {
      float e = expf(Lr[64 + f] - mf);
      Zf += e;
      float g = 1.f / (1.f + expf(-Lr[128 + f]));
      Sf = fmaf(g, e, Sf);
    }
    out[tok0 + tid] = a * (St / Zt) + (1.f - a) * (Sf / Zf);
  }
}

extern "C" void kernel_launch(void* const* d_in, const int* in_sizes, int n_in,
                              void* d_out, int out_size, void* d_ws, size_t ws_size,
                              hipStream_t stream) {
  const float* x       = (const float*)d_in[0];
  const float* W_top   = (const float*)d_in[1];
  const float* b_top   = (const float*)d_in[2];
  const float* W_feat  = (const float*)d_in[3];
  const float* b_feat  = (const float*)d_in[4];
  const float* W_gates = (const float*)d_in[5];
  const float* b_gates = (const float*)d_in[6];
  const float* alpha   = (const float*)d_in[7];
  const int*   nump    = (const int*)d_in[8];
  float*       out     = (float*)d_out;
  ushort*      Wp      = (ushort*)d_ws;      // 16*24576 ushorts = 768 KB

  int n_tok = in_sizes[0] / D_DIM;           // 16384
  hipLaunchKernelGGL(pack_w_kernel, dim3(96), dim3(256), 0, stream,
                     W_top, W_feat, W_gates, Wp);
  hipLaunchKernelGGL(moe_gate_kernel, dim3(n_tok / TOKB), dim3(THREADS), 0, stream,
                     x, Wp, b_top, b_feat, b_gates, alpha, nump, out);
}